// Round 1
// baseline (552.311 us; speedup 1.0000x reference)
//
#include <hip/hip_runtime.h>

#define EMB 1024
#define NHEADS 16
#define HD 64
#define BATCH 4
#define SEQ 2048
#define MTOK (BATCH*SEQ)   // 8192

typedef __bf16 bf16x8 __attribute__((ext_vector_type(8)));
typedef __bf16 bf16x4 __attribute__((ext_vector_type(4)));
typedef float  f32x4  __attribute__((ext_vector_type(4)));

#define MFMA16(a,b,c) __builtin_amdgcn_mfma_f32_16x16x32_bf16(a,b,c,0,0,0)

__device__ __forceinline__ void gload_lds16(const __bf16* g, __bf16* l) {
    // async global->LDS, 16B per lane; LDS dest = wave-uniform base + lane*16
    __builtin_amdgcn_global_load_lds(
        (__attribute__((address_space(1))) void*)(g),
        (__attribute__((address_space(3))) void*)(l), 16, 0, 0);
}

// ---------------------------------------------------------------------------
// fp32 -> bf16 conversion (memory-bound)
// ---------------------------------------------------------------------------
__global__ void cvt_f32_bf16(const float* __restrict__ in, __bf16* __restrict__ out, int n) {
    int i = (blockIdx.x * blockDim.x + threadIdx.x) * 4;
    if (i < n) {
        float4 v = *(const float4*)(in + i);
        bf16x4 o = { (__bf16)v.x, (__bf16)v.y, (__bf16)v.z, (__bf16)v.w };
        *(bf16x4*)(out + i) = o;
    }
}

// ---------------------------------------------------------------------------
// Shared GEMM body: C[128x128] += A[128xK] * B[128xK]^T   (both K-contiguous,
// K = EMB = 1024, BK = 32). 256 threads = 4 waves (2x2), each wave 64x64 as
// 4x4 grid of 16x16x32 MFMAs. global_load_lds staging with 16B-chunk XOR
// swizzle: chunk slot cc at row m holds global k-chunk dq = cc ^ ((m>>1)&3),
// so frag ds_read_b128 hits only 2-way bank aliasing (free).
// ---------------------------------------------------------------------------
__device__ __forceinline__ void gemm_bt_body(
    const __bf16* __restrict__ A, const __bf16* __restrict__ Bw,
    int tileM, int tileN, __bf16* As, __bf16* Bs, f32x4 acc[4][4])
{
    const int tid   = threadIdx.x;
    const int w     = tid >> 6;
    const int lane  = tid & 63;
    const int mlane = lane & 15;
    const int quad  = lane >> 4;
    const int wm    = (w >> 1) * 64;
    const int wn    = (w & 1) * 64;

    const f32x4 fzero = {0.f, 0.f, 0.f, 0.f};
    #pragma unroll
    for (int mi = 0; mi < 4; ++mi)
        #pragma unroll
        for (int ni = 0; ni < 4; ++ni) acc[mi][ni] = fzero;

    for (int kt = 0; kt < EMB; kt += 32) {
        #pragma unroll
        for (int i = 0; i < 2; ++i) {
            int cbase = i * 256 + w * 64;      // wave-uniform chunk base
            int c  = cbase + lane;             // 16B chunk id 0..511
            int m  = c >> 2;                   // tile row
            int dq = (c & 3) ^ ((m >> 1) & 3); // swizzled global k-chunk
            gload_lds16(A  + (size_t)(tileM + m) * EMB + kt + dq * 8, As + cbase * 8);
            gload_lds16(Bw + (size_t)(tileN + m) * EMB + kt + dq * 8, Bs + cbase * 8);
        }
        asm volatile("s_waitcnt vmcnt(0)" ::: "memory");
        __syncthreads();

        bf16x8 af[4], bfr[4];
        #pragma unroll
        for (int mi = 0; mi < 4; ++mi) {
            int row = wm + mi * 16 + mlane;
            af[mi] = *(const bf16x8*)(As + row * 32 + ((quad ^ ((row >> 1) & 3)) * 8));
        }
        #pragma unroll
        for (int ni = 0; ni < 4; ++ni) {
            int row = wn + ni * 16 + mlane;
            bfr[ni] = *(const bf16x8*)(Bs + row * 32 + ((quad ^ ((row >> 1) & 3)) * 8));
        }
        #pragma unroll
        for (int mi = 0; mi < 4; ++mi)
            #pragma unroll
            for (int ni = 0; ni < 4; ++ni)
                acc[mi][ni] = MFMA16(af[mi], bfr[ni], acc[mi][ni]);
        __syncthreads();
    }
}

// ---------------------------------------------------------------------------
// QKV projection: z = 0/1/2 -> Q/K/V.  C = x @ W^T, epilogue scatters to
// [B,H,S,D] bf16.  Softmax scale 0.125 folded into Q (exact pow2).
// ---------------------------------------------------------------------------
__global__ __launch_bounds__(256) void qkv_gemm(
    const __bf16* __restrict__ xb,
    const __bf16* __restrict__ wq, const __bf16* __restrict__ wk, const __bf16* __restrict__ wv,
    __bf16* __restrict__ Qb, __bf16* __restrict__ Kb, __bf16* __restrict__ Vb)
{
    __shared__ __bf16 As[128 * 32];
    __shared__ __bf16 Bs[128 * 32];
    const int z = blockIdx.z;
    const __bf16* W = (z == 0) ? wq : (z == 1) ? wk : wv;
    __bf16* O       = (z == 0) ? Qb : (z == 1) ? Kb : Vb;
    const float scl = (z == 0) ? 0.125f : 1.0f;

    f32x4 acc[4][4];
    gemm_bt_body(xb, W, blockIdx.y * 128, blockIdx.x * 128, As, Bs, acc);

    const int tid = threadIdx.x, w = tid >> 6, lane = tid & 63;
    const int mlane = lane & 15, quad = lane >> 4;
    const int wm = (w >> 1) * 64, wn = (w & 1) * 64;
    #pragma unroll
    for (int mi = 0; mi < 4; ++mi) {
        #pragma unroll
        for (int ni = 0; ni < 4; ++ni) {
            int ncol = blockIdx.x * 128 + wn + ni * 16 + mlane;
            int h = ncol >> 6, d = ncol & 63;
            #pragma unroll
            for (int r = 0; r < 4; ++r) {
                int mr = blockIdx.y * 128 + wm + mi * 16 + quad * 4 + r;
                int b = mr >> 11, s = mr & 2047;
                O[(((size_t)b * NHEADS + h) * SEQ + s) * HD + d] = (__bf16)(acc[mi][ni][r] * scl);
            }
        }
    }
}

// ---------------------------------------------------------------------------
// Output projection: out = attn @ Wo^T, fp32 epilogue
// ---------------------------------------------------------------------------
__global__ __launch_bounds__(256) void out_gemm(
    const __bf16* __restrict__ attnb, const __bf16* __restrict__ wo, float* __restrict__ out)
{
    __shared__ __bf16 As[128 * 32];
    __shared__ __bf16 Bs[128 * 32];
    f32x4 acc[4][4];
    gemm_bt_body(attnb, wo, blockIdx.y * 128, blockIdx.x * 128, As, Bs, acc);

    const int tid = threadIdx.x, w = tid >> 6, lane = tid & 63;
    const int mlane = lane & 15, quad = lane >> 4;
    const int wm = (w >> 1) * 64, wn = (w & 1) * 64;
    #pragma unroll
    for (int mi = 0; mi < 4; ++mi) {
        #pragma unroll
        for (int ni = 0; ni < 4; ++ni) {
            int ncol = blockIdx.x * 128 + wn + ni * 16 + mlane;
            #pragma unroll
            for (int r = 0; r < 4; ++r) {
                int mr = blockIdx.y * 128 + wm + mi * 16 + quad * 4 + r;
                out[(size_t)mr * EMB + ncol] = acc[mi][ni][r];
            }
        }
    }
}

// ---------------------------------------------------------------------------
// Causal flash attention. Block = (64 q-rows, head, batch), 256 thr = 4 waves,
// each wave owns 16 q-rows. Iterate 32-wide t-chunks; K staged [t][d] pad72,
// V staged transposed [d][t] pad40. QK^T: 4 MFMAs -> two 16x16 C-tiles;
// online softmax via quad shuffles; P through per-wave LDS (C->A layout);
// PV: 4 MFMAs. Scale 1/8 already folded into Q.
// ---------------------------------------------------------------------------
__global__ __launch_bounds__(256) void attn_kernel(
    const __bf16* __restrict__ Qb, const __bf16* __restrict__ Kb,
    const __bf16* __restrict__ Vb, __bf16* __restrict__ attnb)
{
    __shared__ __bf16 Ks[32 * 72];
    __shared__ __bf16 Vt[64 * 40];
    __shared__ __bf16 Ps[4 * 16 * 40];

    const int tid = threadIdx.x, w = tid >> 6, lane = tid & 63;
    const int mlane = lane & 15, quad = lane >> 4;
    const int qbase = blockIdx.x * 64;
    const int h = blockIdx.y, b = blockIdx.z;
    const size_t headoff = ((size_t)b * NHEADS + h) * SEQ * HD;
    const __bf16* Qg = Qb + headoff;
    const __bf16* Kg = Kb + headoff;
    const __bf16* Vg = Vb + headoff;

    // Q fragments for this wave's 16 rows (held for whole kernel)
    const int qrow_lane = qbase + w * 16 + mlane;
    bf16x8 aq0 = *(const bf16x8*)(Qg + (size_t)qrow_lane * HD + quad * 8);
    bf16x8 aq1 = *(const bf16x8*)(Qg + (size_t)qrow_lane * HD + 32 + quad * 8);

    float m_run[4], l_run[4], alpha[4];
    f32x4 o_acc[4];
    const f32x4 fzero = {0.f, 0.f, 0.f, 0.f};
    #pragma unroll
    for (int r = 0; r < 4; ++r) { m_run[r] = -3e38f; l_run[r] = 0.f; }
    #pragma unroll
    for (int dt = 0; dt < 4; ++dt) o_acc[dt] = fzero;

    const int qrow0  = qbase + w * 16 + quad * 4;
    const int qw_max = qbase + w * 16 + 15;
    __bf16* Psw = Ps + w * 16 * 40;

    const int nch = (qbase + 63) / 32 + 1;
    for (int c = 0; c < nch; ++c) {
        const int tb = c * 32;
        __syncthreads();   // previous iter's LDS reads complete
        {
            int trow = tid >> 3;
            int d0 = (tid & 7) * 8;
            bf16x8 kv = *(const bf16x8*)(Kg + (size_t)(tb + trow) * HD + d0);
            *(bf16x8*)(Ks + trow * 72 + d0) = kv;
            bf16x8 vv = *(const bf16x8*)(Vg + (size_t)(tb + trow) * HD + d0);
            int rot = tid & 7;  // stagger scalar transpose writes -> 2-way banks
            #pragma unroll
            for (int j = 0; j < 8; ++j) {
                int jj = (j + rot) & 7;
                Vt[(d0 + jj) * 40 + trow] = vv[jj];
            }
        }
        __syncthreads();

        if (tb <= qw_max) {   // wave-uniform causal skip
            f32x4 s0 = fzero, s1 = fzero;
            {
                bf16x8 k0a = *(const bf16x8*)(Ks + mlane * 72 + quad * 8);
                bf16x8 k0b = *(const bf16x8*)(Ks + mlane * 72 + 32 + quad * 8);
                s0 = MFMA16(aq0, k0a, s0);
                s0 = MFMA16(aq1, k0b, s0);
                bf16x8 k1a = *(const bf16x8*)(Ks + (16 + mlane) * 72 + quad * 8);
                bf16x8 k1b = *(const bf16x8*)(Ks + (16 + mlane) * 72 + 32 + quad * 8);
                s1 = MFMA16(aq0, k1a, s1);
                s1 = MFMA16(aq1, k1b, s1);
            }
            #pragma unroll
            for (int r = 0; r < 4; ++r) {
                const int rq = qrow0 + r;
                float v0 = (tb + mlane      <= rq) ? s0[r] : -3e38f;
                float v1 = (tb + 16 + mlane <= rq) ? s1[r] : -3e38f;
                float mx = fmaxf(v0, v1);
                mx = fmaxf(mx, __shfl_xor(mx, 1));
                mx = fmaxf(mx, __shfl_xor(mx, 2));
                mx = fmaxf(mx, __shfl_xor(mx, 4));
                mx = fmaxf(mx, __shfl_xor(mx, 8));
                float mnew = fmaxf(m_run[r], mx);
                float a  = __expf(m_run[r] - mnew);
                float p0 = __expf(v0 - mnew);
                float p1 = __expf(v1 - mnew);
                float rs = p0 + p1;
                rs += __shfl_xor(rs, 1);
                rs += __shfl_xor(rs, 2);
                rs += __shfl_xor(rs, 4);
                rs += __shfl_xor(rs, 8);
                l_run[r] = l_run[r] * a + rs;
                m_run[r] = mnew;
                alpha[r] = a;
                Psw[(quad * 4 + r) * 40 + mlane]      = (__bf16)p0;
                Psw[(quad * 4 + r) * 40 + 16 + mlane] = (__bf16)p1;
            }
            #pragma unroll
            for (int dt = 0; dt < 4; ++dt)
                #pragma unroll
                for (int r = 0; r < 4; ++r) o_acc[dt][r] *= alpha[r];

            bf16x8 pa = *(const bf16x8*)(Psw + mlane * 40 + quad * 8);
            #pragma unroll
            for (int dt = 0; dt < 4; ++dt) {
                bf16x8 vf = *(const bf16x8*)(Vt + (dt * 16 + mlane) * 40 + quad * 8);
                o_acc[dt] = MFMA16(pa, vf, o_acc[dt]);
            }
        }
    }

    // epilogue: normalize and write [B,S,E] bf16
    #pragma unroll
    for (int r = 0; r < 4; ++r) {
        float linv = 1.0f / l_run[r];
        int s = qrow0 + r;
        size_t rowoff = ((size_t)b * SEQ + s) * EMB + h * HD;
        #pragma unroll
        for (int dt = 0; dt < 4; ++dt)
            attnb[rowoff + dt * 16 + mlane] = (__bf16)(o_acc[dt][r] * linv);
    }
}

// ---------------------------------------------------------------------------
extern "C" void kernel_launch(void* const* d_in, const int* in_sizes, int n_in,
                              void* d_out, int out_size, void* d_ws, size_t ws_size,
                              hipStream_t stream) {
    const float* x  = (const float*)d_in[0];
    const float* Wq = (const float*)d_in[1];
    const float* Wk = (const float*)d_in[2];
    const float* Wv = (const float*)d_in[3];
    const float* Wo = (const float*)d_in[4];
    float* out = (float*)d_out;

    char* ws = (char*)d_ws;
    // workspace layout (bytes), all 16B aligned; total 92,274,688
    __bf16* xb    = (__bf16*)(ws);                         // 8192x1024
    __bf16* wqb   = (__bf16*)(ws + 16777216);              // 1024x1024
    __bf16* wkb   = (__bf16*)(ws + 18874368);
    __bf16* wvb   = (__bf16*)(ws + 20971520);
    __bf16* wob   = (__bf16*)(ws + 23068672);
    __bf16* qb    = (__bf16*)(ws + 25165824);              // [B,H,S,D]
    __bf16* kb    = (__bf16*)(ws + 41943040);
    __bf16* vb    = (__bf16*)(ws + 58720256);
    __bf16* attnb = (__bf16*)(ws + 75497472);              // [B,S,E]

    // fp32 -> bf16
    cvt_f32_bf16<<<8192, 256, 0, stream>>>(x,  xb,  MTOK * EMB);
    cvt_f32_bf16<<<1024, 256, 0, stream>>>(Wq, wqb, EMB * EMB);
    cvt_f32_bf16<<<1024, 256, 0, stream>>>(Wk, wkb, EMB * EMB);
    cvt_f32_bf16<<<1024, 256, 0, stream>>>(Wv, wvb, EMB * EMB);
    cvt_f32_bf16<<<1024, 256, 0, stream>>>(Wo, wob, EMB * EMB);

    // Q/K/V projections (scale folded into Q)
    qkv_gemm<<<dim3(EMB / 128, MTOK / 128, 3), 256, 0, stream>>>(xb, wqb, wkb, wvb, qb, kb, vb);

    // causal flash attention
    attn_kernel<<<dim3(SEQ / 64, NHEADS, BATCH), 256, 0, stream>>>(qb, kb, vb, attnb);

    // output projection
    out_gemm<<<dim3(EMB / 128, MTOK / 128, 1), 256, 0, stream>>>(attnb, wob, out);
}

// Round 2
// 282.356 us; speedup vs baseline: 1.9561x; 1.9561x over previous
//
#include <hip/hip_runtime.h>

#define EMB 1024
#define NHEADS 16
#define HD 64
#define BATCH 4
#define SEQ 2048
#define MTOK (BATCH*SEQ)   // 8192

typedef __bf16 bf16x8 __attribute__((ext_vector_type(8)));
typedef __bf16 bf16x4 __attribute__((ext_vector_type(4)));
typedef float  f32x4  __attribute__((ext_vector_type(4)));

#define MFMA16(a,b,c) __builtin_amdgcn_mfma_f32_16x16x32_bf16(a,b,c,0,0,0)

__device__ __forceinline__ void gload_lds16(const __bf16* g, __bf16* l) {
    __builtin_amdgcn_global_load_lds(
        (__attribute__((address_space(1))) void*)(g),
        (__attribute__((address_space(3))) void*)(l), 16, 0, 0);
}

// ---------------------------------------------------------------------------
// fp32 -> bf16 conversion (memory-bound)
// ---------------------------------------------------------------------------
__global__ void cvt_f32_bf16(const float* __restrict__ in, __bf16* __restrict__ out, int n) {
    int i = (blockIdx.x * blockDim.x + threadIdx.x) * 4;
    if (i < n) {
        float4 v = *(const float4*)(in + i);
        bf16x4 o = { (__bf16)v.x, (__bf16)v.y, (__bf16)v.z, (__bf16)v.w };
        *(bf16x4*)(out + i) = o;
    }
}

// ---------------------------------------------------------------------------
// Shared GEMM body: C[128x128] += A[128xK] * B[128xK]^T  (m97-style ladder)
// ---------------------------------------------------------------------------
__device__ __forceinline__ void gemm_bt_body(
    const __bf16* __restrict__ A, const __bf16* __restrict__ Bw,
    int tileM, int tileN, __bf16* As, __bf16* Bs, f32x4 acc[4][4])
{
    const int tid   = threadIdx.x;
    const int w     = tid >> 6;
    const int lane  = tid & 63;
    const int mlane = lane & 15;
    const int quad  = lane >> 4;
    const int wm    = (w >> 1) * 64;
    const int wn    = (w & 1) * 64;

    const f32x4 fzero = {0.f, 0.f, 0.f, 0.f};
    #pragma unroll
    for (int mi = 0; mi < 4; ++mi)
        #pragma unroll
        for (int ni = 0; ni < 4; ++ni) acc[mi][ni] = fzero;

    for (int kt = 0; kt < EMB; kt += 32) {
        #pragma unroll
        for (int i = 0; i < 2; ++i) {
            int cbase = i * 256 + w * 64;
            int c  = cbase + lane;
            int m  = c >> 2;
            int dq = (c & 3) ^ ((m >> 1) & 3);
            gload_lds16(A  + (size_t)(tileM + m) * EMB + kt + dq * 8, As + cbase * 8);
            gload_lds16(Bw + (size_t)(tileN + m) * EMB + kt + dq * 8, Bs + cbase * 8);
        }
        asm volatile("s_waitcnt vmcnt(0)" ::: "memory");
        __syncthreads();

        bf16x8 af[4], bfr[4];
        #pragma unroll
        for (int mi = 0; mi < 4; ++mi) {
            int row = wm + mi * 16 + mlane;
            af[mi] = *(const bf16x8*)(As + row * 32 + ((quad ^ ((row >> 1) & 3)) * 8));
        }
        #pragma unroll
        for (int ni = 0; ni < 4; ++ni) {
            int row = wn + ni * 16 + mlane;
            bfr[ni] = *(const bf16x8*)(Bs + row * 32 + ((quad ^ ((row >> 1) & 3)) * 8));
        }
        #pragma unroll
        for (int mi = 0; mi < 4; ++mi)
            #pragma unroll
            for (int ni = 0; ni < 4; ++ni)
                acc[mi][ni] = MFMA16(af[mi], bfr[ni], acc[mi][ni]);
        __syncthreads();
    }
}

// ---------------------------------------------------------------------------
// QKV projection. Scale 0.125*log2(e) folded into Q (softmax done in exp2).
// ---------------------------------------------------------------------------
__global__ __launch_bounds__(256) void qkv_gemm(
    const __bf16* __restrict__ xb,
    const __bf16* __restrict__ wq, const __bf16* __restrict__ wk, const __bf16* __restrict__ wv,
    __bf16* __restrict__ Qb, __bf16* __restrict__ Kb, __bf16* __restrict__ Vb)
{
    __shared__ __bf16 As[128 * 32];
    __shared__ __bf16 Bs[128 * 32];
    const int z = blockIdx.z;
    const __bf16* W = (z == 0) ? wq : (z == 1) ? wk : wv;
    __bf16* O       = (z == 0) ? Qb : (z == 1) ? Kb : Vb;
    const float scl = (z == 0) ? 0.18033688011112042f : 1.0f;  // 0.125*log2(e) for Q

    f32x4 acc[4][4];
    gemm_bt_body(xb, W, blockIdx.y * 128, blockIdx.x * 128, As, Bs, acc);

    const int tid = threadIdx.x, w = tid >> 6, lane = tid & 63;
    const int mlane = lane & 15, quad = lane >> 4;
    const int wm = (w >> 1) * 64, wn = (w & 1) * 64;
    #pragma unroll
    for (int mi = 0; mi < 4; ++mi) {
        #pragma unroll
        for (int ni = 0; ni < 4; ++ni) {
            int ncol = blockIdx.x * 128 + wn + ni * 16 + mlane;
            int h = ncol >> 6, d = ncol & 63;
            #pragma unroll
            for (int r = 0; r < 4; ++r) {
                int mr = blockIdx.y * 128 + wm + mi * 16 + quad * 4 + r;
                int b = mr >> 11, s = mr & 2047;
                O[(((size_t)b * NHEADS + h) * SEQ + s) * HD + d] = (__bf16)(acc[mi][ni][r] * scl);
            }
        }
    }
}

// ---------------------------------------------------------------------------
// Output projection: out = attn @ Wo^T, fp32 epilogue
// ---------------------------------------------------------------------------
__global__ __launch_bounds__(256) void out_gemm(
    const __bf16* __restrict__ attnb, const __bf16* __restrict__ wo, float* __restrict__ out)
{
    __shared__ __bf16 As[128 * 32];
    __shared__ __bf16 Bs[128 * 32];
    f32x4 acc[4][4];
    gemm_bt_body(attnb, wo, blockIdx.y * 128, blockIdx.x * 128, As, Bs, acc);

    const int tid = threadIdx.x, w = tid >> 6, lane = tid & 63;
    const int mlane = lane & 15, quad = lane >> 4;
    const int wm = (w >> 1) * 64, wn = (w & 1) * 64;
    #pragma unroll
    for (int mi = 0; mi < 4; ++mi) {
        #pragma unroll
        for (int ni = 0; ni < 4; ++ni) {
            int ncol = blockIdx.x * 128 + wn + ni * 16 + mlane;
            #pragma unroll
            for (int r = 0; r < 4; ++r) {
                int mr = blockIdx.y * 128 + wm + mi * 16 + quad * 4 + r;
                out[(size_t)mr * EMB + ncol] = acc[mi][ni][r];
            }
        }
    }
}

// ---------------------------------------------------------------------------
// Causal flash attention, v2.
//  - Block = 4 waves x 32 q-rows = 128 q-rows; processes strip pair
//    {x, 15-x} -> every block does exactly 34 chunk-iterations (balance).
//  - 64-key chunks. Scores computed TRANSPOSED (S^T = K·Q^T) so the key
//    reduction is an in-lane tree + 2 shfl_xor(16/32) (quad dimension).
//  - K staged [key][72] (pad-72: frag reads land 8/bank = b128 minimum).
//  - V staged [key-granule][d][key&7], granule stride 520 elems: transpose
//    writes are 2-way (free), PV B-frag reads are clean b128.
//  - P round-trips LDS (C->A layout), b64 writes (conflict-free), pad-72.
//  - exp2-domain softmax: 0.125*log2(e) pre-folded into Q.
// ---------------------------------------------------------------------------
__global__ __launch_bounds__(256, 2) void attn_kernel(
    const __bf16* __restrict__ Qb, const __bf16* __restrict__ Kb,
    const __bf16* __restrict__ Vb, __bf16* __restrict__ attnb)
{
    __shared__ __bf16 Ks[64 * 72];
    __shared__ __bf16 Vt[8 * 520];
    __shared__ __bf16 Ps[4 * 32 * 72];

    const int tid = threadIdx.x, w = tid >> 6, lane = tid & 63;
    const int mlane = lane & 15, quad = lane >> 4;
    const int h = blockIdx.y, b = blockIdx.z;
    const size_t headoff = ((size_t)b * NHEADS + h) * SEQ * HD;
    const __bf16* Qg = Qb + headoff;
    const __bf16* Kg = Kb + headoff;
    const __bf16* Vg = Vb + headoff;
    __bf16* Psw = Ps + w * 32 * 72;

    const int st_t = lane;       // staging: row within 64-key chunk
    const int st_d = w * 16;     // staging: d-offset (16 wide per wave)

    for (int sp = 0; sp < 2; ++sp) {
        const int strip = sp ? (15 - blockIdx.x) : blockIdx.x;
        const int qbase = strip * 128;
        const int qw    = qbase + w * 32;     // wave's first q-row

        // Q B-frags (held in regs for the strip)
        bf16x8 bq[2][2];
        #pragma unroll
        for (int nt = 0; nt < 2; ++nt)
            #pragma unroll
            for (int ks = 0; ks < 2; ++ks)
                bq[nt][ks] = *(const bf16x8*)(Qg + (size_t)(qw + nt * 16 + mlane) * HD + ks * 32 + quad * 8);

        float m_run[2] = {-3e38f, -3e38f};
        float l_run[2] = {0.f, 0.f};
        f32x4 o[2][4];
        const f32x4 fzero = {0.f, 0.f, 0.f, 0.f};
        #pragma unroll
        for (int qt = 0; qt < 2; ++qt)
            #pragma unroll
            for (int dt = 0; dt < 4; ++dt) o[qt][dt] = fzero;

        const int nch = qbase / 64 + 2;
        for (int c = 0; c < nch; ++c) {
            const int tb = c * 64;
            __syncthreads();   // previous iteration's LDS reads complete
            {
                const __bf16* kp = Kg + (size_t)(tb + st_t) * HD + st_d;
                bf16x8 k0 = *(const bf16x8*)kp;
                bf16x8 k1 = *(const bf16x8*)(kp + 8);
                *(bf16x8*)(Ks + st_t * 72 + st_d)     = k0;
                *(bf16x8*)(Ks + st_t * 72 + st_d + 8) = k1;
                const __bf16* vp = Vg + (size_t)(tb + st_t) * HD + st_d;
                bf16x8 v0 = *(const bf16x8*)vp;
                bf16x8 v1 = *(const bf16x8*)(vp + 8);
                __bf16* vd = Vt + (st_t >> 3) * 520 + (st_t & 7);
                #pragma unroll
                for (int j = 0; j < 8; ++j) vd[(st_d + j) * 8]     = v0[j];
                #pragma unroll
                for (int j = 0; j < 8; ++j) vd[(st_d + 8 + j) * 8] = v1[j];
            }
            __syncthreads();
            if (tb > qw + 31) continue;   // wave-uniform causal skip

            // ---- S^T = K · Q^T : rows=keys(quad*4+r), cols=q(mlane) ----
            f32x4 s[4][2];
            #pragma unroll
            for (int mt = 0; mt < 4; ++mt) {
                bf16x8 ak0 = *(const bf16x8*)(Ks + (mt * 16 + mlane) * 72 + quad * 8);
                bf16x8 ak1 = *(const bf16x8*)(Ks + (mt * 16 + mlane) * 72 + 32 + quad * 8);
                f32x4 z = fzero;
                s[mt][0] = MFMA16(ak1, bq[0][1], MFMA16(ak0, bq[0][0], z));
                s[mt][1] = MFMA16(ak1, bq[1][1], MFMA16(ak0, bq[1][0], z));
            }

            if (tb + 63 > qw) {   // only diag chunks need masking
                #pragma unroll
                for (int nt = 0; nt < 2; ++nt) {
                    int qrel = qw + nt * 16 + mlane - tb - quad * 4;
                    #pragma unroll
                    for (int mt = 0; mt < 4; ++mt)
                        #pragma unroll
                        for (int r = 0; r < 4; ++r)
                            if (mt * 16 + r > qrel) s[mt][nt][r] = -3e38f;
                }
            }

            // ---- online softmax (per q-col = per lane&15) ----
            float alpha[2];
            #pragma unroll
            for (int nt = 0; nt < 2; ++nt) {
                float mx = s[0][nt][0];
                #pragma unroll
                for (int mt = 0; mt < 4; ++mt)
                    #pragma unroll
                    for (int r = 0; r < 4; ++r) mx = fmaxf(mx, s[mt][nt][r]);
                mx = fmaxf(mx, __shfl_xor(mx, 16));
                mx = fmaxf(mx, __shfl_xor(mx, 32));
                float mnew = fmaxf(m_run[nt], mx);
                alpha[nt]  = __builtin_amdgcn_exp2f(m_run[nt] - mnew);
                m_run[nt]  = mnew;

                f32x4 ps4 = fzero;
                #pragma unroll
                for (int mt = 0; mt < 4; ++mt) {
                    #pragma unroll
                    for (int r = 0; r < 4; ++r)
                        s[mt][nt][r] = __builtin_amdgcn_exp2f(s[mt][nt][r] - mnew);
                    ps4 += s[mt][nt];
                    bf16x4 pb = { (__bf16)s[mt][nt][0], (__bf16)s[mt][nt][1],
                                  (__bf16)s[mt][nt][2], (__bf16)s[mt][nt][3] };
                    *(bf16x4*)(Psw + (nt * 16 + mlane) * 72 + mt * 16 + quad * 4) = pb;
                }
                float rs = (ps4[0] + ps4[1]) + (ps4[2] + ps4[3]);
                rs += __shfl_xor(rs, 16);
                rs += __shfl_xor(rs, 32);
                l_run[nt] = l_run[nt] * alpha[nt] + rs;
            }

            // ---- rescale O by alpha (alpha lives at q=lane&15; O-rows at quad*4+r) ----
            #pragma unroll
            for (int qt = 0; qt < 2; ++qt)
                #pragma unroll
                for (int r = 0; r < 4; ++r) {
                    float ar = __shfl(alpha[qt], quad * 4 + r);
                    #pragma unroll
                    for (int dt = 0; dt < 4; ++dt) o[qt][dt][r] *= ar;
                }

            // ---- PV: O[q][d] += P[q][k] V^T[d][k] ----
            bf16x8 ap[2][2];
            #pragma unroll
            for (int qt = 0; qt < 2; ++qt)
                #pragma unroll
                for (int ks = 0; ks < 2; ++ks)
                    ap[qt][ks] = *(const bf16x8*)(Psw + (qt * 16 + mlane) * 72 + ks * 32 + quad * 8);
            #pragma unroll
            for (int ks = 0; ks < 2; ++ks)
                #pragma unroll
                for (int dt = 0; dt < 4; ++dt) {
                    bf16x8 bv = *(const bf16x8*)(Vt + (ks * 4 + quad) * 520 + (dt * 16 + mlane) * 8);
                    #pragma unroll
                    for (int qt = 0; qt < 2; ++qt)
                        o[qt][dt] = MFMA16(ap[qt][ks], bv, o[qt][dt]);
                }
        }

        // ---- epilogue: normalize, write [B,S,E] bf16 ----
        #pragma unroll
        for (int qt = 0; qt < 2; ++qt)
            #pragma unroll
            for (int r = 0; r < 4; ++r) {
                float lr = __shfl(l_run[qt], quad * 4 + r);
                float linv = 1.0f / lr;
                int q = qw + qt * 16 + quad * 4 + r;
                size_t rowoff = ((size_t)b * SEQ + q) * EMB + h * HD;
                #pragma unroll
                for (int dt = 0; dt < 4; ++dt)
                    attnb[rowoff + dt * 16 + mlane] = (__bf16)(o[qt][dt][r] * linv);
            }
    }
}

// ---------------------------------------------------------------------------
extern "C" void kernel_launch(void* const* d_in, const int* in_sizes, int n_in,
                              void* d_out, int out_size, void* d_ws, size_t ws_size,
                              hipStream_t stream) {
    const float* x  = (const float*)d_in[0];
    const float* Wq = (const float*)d_in[1];
    const float* Wk = (const float*)d_in[2];
    const float* Wv = (const float*)d_in[3];
    const float* Wo = (const float*)d_in[4];
    float* out = (float*)d_out;

    char* ws = (char*)d_ws;
    __bf16* xb    = (__bf16*)(ws);
    __bf16* wqb   = (__bf16*)(ws + 16777216);
    __bf16* wkb   = (__bf16*)(ws + 18874368);
    __bf16* wvb   = (__bf16*)(ws + 20971520);
    __bf16* wob   = (__bf16*)(ws + 23068672);
    __bf16* qb    = (__bf16*)(ws + 25165824);
    __bf16* kb    = (__bf16*)(ws + 41943040);
    __bf16* vb    = (__bf16*)(ws + 58720256);
    __bf16* attnb = (__bf16*)(ws + 75497472);

    cvt_f32_bf16<<<8192, 256, 0, stream>>>(x,  xb,  MTOK * EMB);
    cvt_f32_bf16<<<1024, 256, 0, stream>>>(Wq, wqb, EMB * EMB);
    cvt_f32_bf16<<<1024, 256, 0, stream>>>(Wk, wkb, EMB * EMB);
    cvt_f32_bf16<<<1024, 256, 0, stream>>>(Wv, wvb, EMB * EMB);
    cvt_f32_bf16<<<1024, 256, 0, stream>>>(Wo, wob, EMB * EMB);

    qkv_gemm<<<dim3(EMB / 128, MTOK / 128, 3), 256, 0, stream>>>(xb, wqb, wkb, wvb, qb, kb, vb);

    attn_kernel<<<dim3(8, NHEADS, BATCH), 256, 0, stream>>>(qb, kb, vb, attnb);

    out_gemm<<<dim3(EMB / 128, MTOK / 128, 1), 256, 0, stream>>>(attnb, wob, out);
}